// Round 2
// baseline (331.727 us; speedup 1.0000x reference)
//
#include <hip/hip_runtime.h>
#include <math.h>

// Problem constants: N=100000, E=1600000, D_IN=D_OUT=128
#define D 128
#define BSHIFT 9              // 512 dst rows per bucket
#define BROWS 512
#define TILE 8192             // edges per binA workgroup
constexpr float BN_EPS = 1e-5f;
typedef unsigned long long ull;

// bf16 helpers (manual, RNE) ------------------------------------------------
__device__ __forceinline__ unsigned f2bf_rne(float f) {
    unsigned u = __float_as_uint(f);
    return (u + 0x7FFFu + ((u >> 16) & 1u)) >> 16;
}
__device__ __forceinline__ float bf_lo(unsigned u) { return __uint_as_float(u << 16); }
__device__ __forceinline__ float bf_hi(unsigned u) { return __uint_as_float(u & 0xFFFF0000u); }

// ---------------------------------------------------------------------------
// phase1: fused dispatch. Blocks [0,nwgA) run binA (bucket sort pass A);
// blocks [nwgA, nwgA+ngemm) run gemm_pack (y = x@W, packed to bf16).
// Disjoint inputs -> they overlap; critical path = max, not sum.
// binA's 3KB of LDS is aliased into gemm's 80KB buffer so the LDS footprint
// stays 80KB -> 2 blocks/CU either way.
// ---------------------------------------------------------------------------
__global__ __launch_bounds__(256) void phase1_kernel(
    const float* __restrict__ A,
    const float* __restrict__ W,
    unsigned* __restrict__ yb,
    int n,
    const int* __restrict__ esrc, const int* __restrict__ edst,
    const float* __restrict__ evals,
    uint2* __restrict__ slices,        // [nwgA * TILE]
    int* __restrict__ ofs_t,           // [(B+1) * nwgA], transposed [bucket][wg]
    int B, int nwgA, int E)
{
    __shared__ __align__(16) char smem[81920];
    const int tid = threadIdx.x;

    if ((int)blockIdx.x < nwgA) {
        // ------------------- binA: coarse bucket sort -------------------
        int* h   = (int*)smem;
        int* ps  = h + 256;
        int* cur = ps + 256;
        const int wg = blockIdx.x;
        const int e0 = wg * TILE;
        const int e1 = min(e0 + TILE, E);

        h[tid] = 0;
        __syncthreads();
        for (int e = e0 + tid; e < e1; e += 256)
            atomicAdd(&h[edst[e] >> BSHIFT], 1);
        __syncthreads();

        const int v = h[tid];
        ps[tid] = v;
        __syncthreads();
        for (int off = 1; off < 256; off <<= 1) {
            int t = (tid >= off) ? ps[tid - off] : 0;
            __syncthreads();
            if (tid >= off) ps[tid] += t;
            __syncthreads();
        }
        const int excl = ps[tid] - v;
        if (tid < B) {
            cur[tid] = excl;
            ofs_t[(size_t)tid * nwgA + wg] = excl;
        }
        if (tid == 0) ofs_t[(size_t)B * nwgA + wg] = e1 - e0;  // sentinel
        __syncthreads();

        uint2* slice = slices + (size_t)wg * TILE;
        for (int e = e0 + tid; e < e1; e += 256) {
            int d = edst[e];
            int b = d >> BSHIFT;
            int p = atomicAdd(&cur[b], 1);
            uint2 rec;
            rec.x = (unsigned)(d & (BROWS - 1)) | ((unsigned)esrc[e] << BSHIFT);
            rec.y = __float_as_uint(evals[e]);
            slice[p] = rec;
        }
    } else {
        // ------------------- gemm_pack: y = x@W -> bf16 -------------------
        float* sW = (float*)smem;                          // 64 KB
        float (*sA)[128] = (float(*)[128])(smem + 65536);  // 16 KB

        const float4* W4  = (const float4*)W;
        float4*       sW4 = (float4*)sW;
#pragma unroll
        for (int i = 0; i < 16; i++) sW4[tid + 256 * i] = W4[tid + 256 * i];

        const int row0 = (blockIdx.x - nwgA) * 32;
        const float4* A4  = (const float4*)(A + (size_t)row0 * D);
        float4*       sA4 = (float4*)&sA[0][0];
#pragma unroll
        for (int i = 0; i < 4; i++) {
            int idx = tid + 256 * i;
            sA4[idx] = ((size_t)row0 * D + (size_t)idx * 4 < (size_t)n * D)
                           ? A4[idx] : make_float4(0.f, 0.f, 0.f, 0.f);
        }
        __syncthreads();

        const int tx = tid & 31;
        const int ty = tid >> 5;
        const int c0 = tx * 4;

        float acc[4][4] = {};
        for (int k0 = 0; k0 < 128; k0 += 4) {
            float4 a[4];
#pragma unroll
            for (int j = 0; j < 4; j++)
                a[j] = *(const float4*)&sA[ty + 8 * j][k0];
#pragma unroll
            for (int kk = 0; kk < 4; kk++) {
                const float4 w = *(const float4*)&sW[(k0 + kk) * 128 + c0];
                const float ak[4] = { kk == 0 ? a[0].x : kk == 1 ? a[0].y : kk == 2 ? a[0].z : a[0].w,
                                      kk == 0 ? a[1].x : kk == 1 ? a[1].y : kk == 2 ? a[1].z : a[1].w,
                                      kk == 0 ? a[2].x : kk == 1 ? a[2].y : kk == 2 ? a[2].z : a[2].w,
                                      kk == 0 ? a[3].x : kk == 1 ? a[3].y : kk == 2 ? a[3].z : a[3].w };
#pragma unroll
                for (int j = 0; j < 4; j++) {
                    acc[j][0] += ak[j] * w.x;
                    acc[j][1] += ak[j] * w.y;
                    acc[j][2] += ak[j] * w.z;
                    acc[j][3] += ak[j] * w.w;
                }
            }
        }

#pragma unroll
        for (int j = 0; j < 4; j++) {
            const int row = row0 + ty + 8 * j;
            if (row < n) {
                uint2 o;
                o.x = f2bf_rne(acc[j][0]) | (f2bf_rne(acc[j][1]) << 16);
                o.y = f2bf_rne(acc[j][2]) | (f2bf_rne(acc[j][3]) << 16);
                ((uint2*)(yb + (size_t)row * 64))[tx] = o;
            }
        }
    }
}

// ---------------------------------------------------------------------------
// binB: one 1024-thread wg (16 waves) per bucket.
// Bucket base = sum over wg of ofs_t[b][wg].
// ---------------------------------------------------------------------------
__global__ __launch_bounds__(1024) void binB_kernel(
    const uint2* __restrict__ slices,
    const int* __restrict__ ofs_t,
    int* __restrict__ rowptr,          // [n], end-form
    ull* __restrict__ csr,             // [E]
    int B, int nwgA, int n)
{
    __shared__ int srow[256];
    __shared__ int erow[256];
    __shared__ int red[256];
    __shared__ int hist[BROWS];
    __shared__ int curs[BROWS];
    __shared__ int ps[BROWS];
    __shared__ int s_bbase;

    const int tid  = threadIdx.x;
    const int b    = blockIdx.x;
    const int w    = tid >> 6;
    const int lane = tid & 63;

    for (int i = tid; i < nwgA; i += 1024) {
        srow[i] = ofs_t[(size_t)b * nwgA + i];
        erow[i] = ofs_t[(size_t)(b + 1) * nwgA + i];
    }
    if (tid < BROWS) hist[tid] = 0;
    __syncthreads();

    if (tid < 256) red[tid] = (tid < nwgA) ? srow[tid] : 0;
    __syncthreads();
    for (int off = 128; off > 0; off >>= 1) {
        if (tid < off) red[tid] += red[tid + off];
        __syncthreads();
    }
    if (tid == 0) s_bbase = red[0];
    __syncthreads();

    // pass 1: in-bucket row histogram
    for (int wg = w; wg < nwgA; wg += 16) {
        const int s = srow[wg];
        const int e = erow[wg];
        const uint2* run = slices + (size_t)wg * TILE;
        for (int i = s + lane; i < e; i += 64)
            atomicAdd(&hist[run[i].x & (BROWS - 1)], 1);
    }
    __syncthreads();

    int v0 = 0;
    if (tid < BROWS) { v0 = hist[tid]; ps[tid] = v0; }
    __syncthreads();
    for (int off = 1; off < BROWS; off <<= 1) {
        int t = 0;
        if (tid < BROWS && tid >= off) t = ps[tid - off];
        __syncthreads();
        if (tid < BROWS) ps[tid] += t;
        __syncthreads();
    }
    if (tid < BROWS) {
        const int excl = s_bbase + ps[tid] - v0;
        curs[tid] = excl;                       // row start
        const int r = (b << BSHIFT) + tid;
        if (r < n) rowptr[r] = excl + v0;       // row end
    }
    __syncthreads();

    // pass 2: scatter into final CSR positions (bucket-private window)
    for (int wg = w; wg < nwgA; wg += 16) {
        const int s = srow[wg];
        const int e = erow[wg];
        const uint2* run = slices + (size_t)wg * TILE;
        for (int i = s + lane; i < e; i += 64) {
            uint2 r = run[i];
            int pos = atomicAdd(&curs[r.x & (BROWS - 1)], 1);
            csr[pos] = ((ull)r.y << 32) | (r.x >> BSHIFT);
        }
    }
}

// ---------------------------------------------------------------------------
// CSR SpMM + fused column stats — round-9.
//
// Round-8 post-mortem: the pair-gather/flatten rewrite REGRESSED (104->127us):
// VGPR 28->52, occupancy 51->34%, VALUBusy up from bookkeeping. Lesson: the
// round-7 simple 8-edge unroll body was already near-optimal per-wave; the
// limiter is WAVES IN FLIGHT. Round-7 occupancy was GRID-limited: 28 VGPR
// allows 8 blocks/CU (capacity 2048 resident blocks) but grid was only 1563.
//
// Round-9: keep the round-7 body verbatim; 8 rows/wave (grid 3125 blocks =
// 1.5x resident capacity -> occupancy saturates, smaller tail); rowptr staged
// to LDS once per block (kills the 2 dependent global loads per row restart).
// ---------------------------------------------------------------------------
__global__ __launch_bounds__(256) void spmm_stats_kernel(
    const unsigned* __restrict__ yb,
    const int* __restrict__ rowptr,   // end-form
    const ull* __restrict__ csr,
    float* __restrict__ h,
    float* __restrict__ stats,        // [0..127]=sum, [128..255]=sumsq, zeroed
    int n)
{
    __shared__ int   rp[33];
    __shared__ float ssum[128];
    __shared__ float ssq[128];
    const int tid  = threadIdx.x;
    const int wv   = tid >> 6;
    const int lane = tid & 63;
    const int blockRow0 = blockIdx.x * 32;
    const int rbase = blockRow0 + wv * 8;

    if (tid < 128) { ssum[tid] = 0.f; ssq[tid] = 0.f; }
    if (tid < 33) {
        int idx = blockRow0 + tid - 1;          // row whose END we need
        rp[tid] = (idx < 0) ? 0 : rowptr[min(idx, n - 1)];
    }
    __syncthreads();

    float sx = 0.f, sy = 0.f, qx = 0.f, qy = 0.f;
    for (int i = 0; i < 8; i++) {
        const int r = rbase + i;
        if (r >= n) break;
        const int start = rp[r - blockRow0];
        const int end   = rp[r - blockRow0 + 1];

        float ax = 0.f, ay = 0.f;
        int e = start;
        for (; e + 7 < end; e += 8) {
            ull e0 = csr[e],     e1 = csr[e + 1], e2 = csr[e + 2], e3 = csr[e + 3];
            ull e4 = csr[e + 4], e5 = csr[e + 5], e6 = csr[e + 6], e7 = csr[e + 7];
            unsigned u0 = yb[(size_t)(unsigned)e0 * 64 + lane];
            unsigned u1 = yb[(size_t)(unsigned)e1 * 64 + lane];
            unsigned u2 = yb[(size_t)(unsigned)e2 * 64 + lane];
            unsigned u3 = yb[(size_t)(unsigned)e3 * 64 + lane];
            unsigned u4 = yb[(size_t)(unsigned)e4 * 64 + lane];
            unsigned u5 = yb[(size_t)(unsigned)e5 * 64 + lane];
            unsigned u6 = yb[(size_t)(unsigned)e6 * 64 + lane];
            unsigned u7 = yb[(size_t)(unsigned)e7 * 64 + lane];
            float v0 = __uint_as_float((unsigned)(e0 >> 32));
            float v1 = __uint_as_float((unsigned)(e1 >> 32));
            float v2 = __uint_as_float((unsigned)(e2 >> 32));
            float v3 = __uint_as_float((unsigned)(e3 >> 32));
            float v4 = __uint_as_float((unsigned)(e4 >> 32));
            float v5 = __uint_as_float((unsigned)(e5 >> 32));
            float v6 = __uint_as_float((unsigned)(e6 >> 32));
            float v7 = __uint_as_float((unsigned)(e7 >> 32));
            ax += v0 * bf_lo(u0) + v1 * bf_lo(u1) + v2 * bf_lo(u2) + v3 * bf_lo(u3)
                + v4 * bf_lo(u4) + v5 * bf_lo(u5) + v6 * bf_lo(u6) + v7 * bf_lo(u7);
            ay += v0 * bf_hi(u0) + v1 * bf_hi(u1) + v2 * bf_hi(u2) + v3 * bf_hi(u3)
                + v4 * bf_hi(u4) + v5 * bf_hi(u5) + v6 * bf_hi(u6) + v7 * bf_hi(u7);
        }
        for (; e + 3 < end; e += 4) {
            ull e0 = csr[e], e1 = csr[e + 1], e2 = csr[e + 2], e3 = csr[e + 3];
            unsigned u0 = yb[(size_t)(unsigned)e0 * 64 + lane];
            unsigned u1 = yb[(size_t)(unsigned)e1 * 64 + lane];
            unsigned u2 = yb[(size_t)(unsigned)e2 * 64 + lane];
            unsigned u3 = yb[(size_t)(unsigned)e3 * 64 + lane];
            float v0 = __uint_as_float((unsigned)(e0 >> 32));
            float v1 = __uint_as_float((unsigned)(e1 >> 32));
            float v2 = __uint_as_float((unsigned)(e2 >> 32));
            float v3 = __uint_as_float((unsigned)(e3 >> 32));
            ax += v0 * bf_lo(u0) + v1 * bf_lo(u1) + v2 * bf_lo(u2) + v3 * bf_lo(u3);
            ay += v0 * bf_hi(u0) + v1 * bf_hi(u1) + v2 * bf_hi(u2) + v3 * bf_hi(u3);
        }
        for (; e < end; e++) {
            ull ed = csr[e];
            unsigned u = yb[(size_t)(unsigned)ed * 64 + lane];
            float v = __uint_as_float((unsigned)(ed >> 32));
            ax += v * bf_lo(u);
            ay += v * bf_hi(u);
        }
        ((float2*)(h + (size_t)r * D))[lane] = make_float2(ax, ay);
        sx += ax; sy += ay; qx += ax * ax; qy += ay * ay;
    }

    atomicAdd(&ssum[2 * lane],     sx);
    atomicAdd(&ssum[2 * lane + 1], sy);
    atomicAdd(&ssq[2 * lane],      qx);
    atomicAdd(&ssq[2 * lane + 1],  qy);
    __syncthreads();
    if (tid < 128) {
        atomicAdd(&stats[tid],       ssum[tid]);
        atomicAdd(&stats[128 + tid], ssq[tid]);
    }
}

// ---------------------------------------------------------------------------
// In-place BatchNorm apply. Linear bias cancels under BN -> omitted.
// ---------------------------------------------------------------------------
__global__ __launch_bounds__(256) void bn_apply_kernel(
    float* __restrict__ h,
    const float* __restrict__ stats,
    const float* __restrict__ gamma,
    const float* __restrict__ beta,
    int n)
{
    __shared__ float s_scale[128];
    __shared__ float s_shift[128];
    const int tid = threadIdx.x;
    if (tid < 128) {
        const float invn = 1.0f / (float)n;
        const float mean = stats[tid] * invn;
        const float var  = stats[128 + tid] * invn - mean * mean;
        const float inv  = rsqrtf(var + BN_EPS);
        const float g    = gamma[tid] * inv;
        s_scale[tid] = g;
        s_shift[tid] = beta[tid] - mean * g;
    }
    __syncthreads();

    float4* h4 = (float4*)h;
    const size_t total = (size_t)n * D / 4;
    const size_t stride = (size_t)gridDim.x * blockDim.x;
    for (size_t i = (size_t)blockIdx.x * blockDim.x + tid; i < total; i += stride) {
        float4 v = h4[i];
        const int c = (int)((i * 4) & (D - 1));
        v.x = v.x * s_scale[c]     + s_shift[c];
        v.y = v.y * s_scale[c + 1] + s_shift[c + 1];
        v.z = v.z * s_scale[c + 2] + s_shift[c + 2];
        v.w = v.w * s_scale[c + 3] + s_shift[c + 3];
        h4[i] = v;
    }
}

// ---------------------------------------------------------------------------
// Fallback (ws too small / shape mismatch): atomic SpMM + GEMM w/ stats.
// ---------------------------------------------------------------------------
__global__ __launch_bounds__(256) void spmm_atomic_kernel(
    const float* __restrict__ x,
    const int* __restrict__ esrc, const int* __restrict__ edst,
    const float* __restrict__ eval, float* __restrict__ agg, int E)
{
    int wave  = (blockIdx.x * blockDim.x + threadIdx.x) >> 6;
    int lane  = threadIdx.x & 63;
    int nwave = (gridDim.x * blockDim.x) >> 6;
    for (int e = wave; e < E; e += nwave) {
        int   s = esrc[e];
        int   d = edst[e];
        float v = eval[e];
        const float2 xv = ((const float2*)(x + (size_t)s * D))[lane];
        float* ar = agg + (size_t)d * D + lane * 2;
        atomicAdd(ar,     xv.x * v);
        atomicAdd(ar + 1, xv.y * v);
    }
}

__global__ __launch_bounds__(256) void gemm_stats_kernel(
    const float* __restrict__ A,
    const float* __restrict__ W,
    float* __restrict__ h,
    float* __restrict__ stats,
    int n)
{
    __shared__ float sW[128 * 128];
    __shared__ float sA[32][128];
    const int tid = threadIdx.x;
    const float4* W4  = (const float4*)W;
    float4*       sW4 = (float4*)sW;
#pragma unroll
    for (int i = 0; i < 16; i++) sW4[tid + 256 * i] = W4[tid + 256 * i];
    const int row0 = blockIdx.x * 32;
    const float4* A4  = (const float4*)(A + (size_t)row0 * D);
    float4*       sA4 = (float4*)&sA[0][0];
#pragma unroll
    for (int i = 0; i < 4; i++) {
        int idx = tid + 256 * i;
        sA4[idx] = ((size_t)row0 * D + (size_t)idx * 4 < (size_t)n * D)
                       ? A4[idx] : make_float4(0.f, 0.f, 0.f, 0.f);
    }
    __syncthreads();
    const int tx = tid & 31, ty = tid >> 5, c0 = tx * 4;
    float acc[4][4] = {};
    for (int k = 0; k < 128; k++) {
        const float4 w = *(const float4*)&sW[k * 128 + c0];
#pragma unroll
        for (int j = 0; j < 4; j++) {
            const float a = sA[ty + 8 * j][k];
            acc[j][0] += a * w.x; acc[j][1] += a * w.y;
            acc[j][2] += a * w.z; acc[j][3] += a * w.w;
        }
    }
#pragma unroll
    for (int j = 0; j < 4; j++) {
        const int row = row0 + ty + 8 * j;
        if (row < n)
            *(float4*)&h[(size_t)row * D + c0] =
                make_float4(acc[j][0], acc[j][1], acc[j][2], acc[j][3]);
    }
    __syncthreads();
    float* csum = &sA[0][0];
    float* csq  = csum + 128;
    if (tid < 128) { csum[tid] = 0.f; csq[tid] = 0.f; }
    __syncthreads();
#pragma unroll
    for (int c = 0; c < 4; c++) {
        float s = 0.f, q = 0.f;
#pragma unroll
        for (int j = 0; j < 4; j++) { s += acc[j][c]; q += acc[j][c] * acc[j][c]; }
        atomicAdd(&csum[c0 + c], s);
        atomicAdd(&csq[c0 + c], q);
    }
    __syncthreads();
    if (tid < 128) {
        atomicAdd(&stats[tid],       csum[tid]);
        atomicAdd(&stats[128 + tid], csq[tid]);
    }
}

// ---------------------------------------------------------------------------
extern "C" void kernel_launch(void* const* d_in, const int* in_sizes, int n_in,
                              void* d_out, int out_size, void* d_ws, size_t ws_size,
                              hipStream_t stream)
{
    const float* x     = (const float*)d_in[0];
    const int*   esrc  = (const int*)d_in[1];
    const int*   edst  = (const int*)d_in[2];
    const float* evals = (const float*)d_in[3];
    const float* W     = (const float*)d_in[4];
    // d_in[5] = bias: unused — cancels exactly under BatchNorm.
    const float* gamma = (const float*)d_in[6];
    const float* beta  = (const float*)d_in[7];
    float* out = (float*)d_out;

    const int n = in_sizes[0] / D;   // 100000
    const int E = in_sizes[1];       // 1600000

    const int B     = (n + BROWS - 1) >> BSHIFT;   // 196 buckets
    const int nwgA  = (E + TILE - 1) / TILE;       // 196 tiles
    const int ngemm = (n + 31) / 32;               // 3125 gemm blocks

    // Workspace (word-indexed):
    //   yb      [n*64]            25.6 MB (packed bf16 y = x@W)
    //   stats   [256]             zeroed (1KB memset)
    //   ofs_t   [(B+1)*nwgA]      ~155 KB (transposed: [bucket][wg])
    //   rowptr  [n]
    //   (pad to even word)
    //   slices  uint2[nwgA*TILE]  12.85 MB
    //   csr     ull  [E]          12.8 MB
    unsigned* yb     = (unsigned*)d_ws;
    float*    stats  = (float*)(yb + (size_t)n * 64);
    int*      ofs_t  = (int*)(stats + 256);
    int*      rowptr = ofs_t + (size_t)(B + 1) * nwgA;
    size_t    w_off  = (size_t)n * 64 + 256 + (size_t)(B + 1) * nwgA + n;
    w_off += (w_off & 1);                          // 8B alignment
    uint2*    slices = (uint2*)((unsigned*)d_ws + w_off);
    ull*      csr    = (ull*)(slices + (size_t)nwgA * TILE);
    const size_t need = (w_off + (size_t)nwgA * TILE * 2 + (size_t)E * 2) * 4;

    if (ws_size >= need && B <= 256 && nwgA <= 256) {
        hipMemsetAsync(stats, 0, 256 * 4, stream);
        phase1_kernel<<<nwgA + ngemm, 256, 0, stream>>>(
            x, W, yb, n, esrc, edst, evals, slices, ofs_t, B, nwgA, E);
        binB_kernel<<<B, 1024, 0, stream>>>(
            slices, ofs_t, rowptr, csr, B, nwgA, n);
        spmm_stats_kernel<<<(n + 31) / 32, 256, 0, stream>>>(
            yb, rowptr, csr, out, stats, n);
        bn_apply_kernel<<<2048, 256, 0, stream>>>(out, stats, gamma, beta, n);
    } else {
        // fallback: fp32 atomic-scatter path
        float* agg = (float*)d_ws;
        float* st  = agg + (size_t)n * D;
        hipMemsetAsync(d_ws, 0, ((size_t)n * D + 256) * 4, stream);
        spmm_atomic_kernel<<<4096, 256, 0, stream>>>(x, esrc, edst, evals, agg, E);
        gemm_stats_kernel<<<(n + 31) / 32, 256, 0, stream>>>(agg, W, out, st, n);
        bn_apply_kernel<<<2048, 256, 0, stream>>>(out, st, gamma, beta, n);
    }
}

// Round 3
// 308.998 us; speedup vs baseline: 1.0736x; 1.0736x over previous
//
#include <hip/hip_runtime.h>
#include <math.h>

// Problem constants: N=100000, E=1600000, D_IN=D_OUT=128
#define D 128
#define BSHIFT 9              // 512 dst rows per bucket
#define BROWS 512
#define TILE 8192             // edges per binA workgroup
constexpr float BN_EPS = 1e-5f;
typedef unsigned long long ull;

// bf16 helpers (manual, RNE) ------------------------------------------------
__device__ __forceinline__ unsigned f2bf_rne(float f) {
    unsigned u = __float_as_uint(f);
    return (u + 0x7FFFu + ((u >> 16) & 1u)) >> 16;
}
__device__ __forceinline__ float bf_lo(unsigned u) { return __uint_as_float(u << 16); }
__device__ __forceinline__ float bf_hi(unsigned u) { return __uint_as_float(u & 0xFFFF0000u); }

// ---------------------------------------------------------------------------
// phase1: fused dispatch. Blocks [0,nwgA) run binA (bucket sort pass A);
// blocks [nwgA, nwgA+ngemm) run gemm_pack (y = x@W, packed to bf16).
// ---------------------------------------------------------------------------
__global__ __launch_bounds__(256) void phase1_kernel(
    const float* __restrict__ A,
    const float* __restrict__ W,
    unsigned* __restrict__ yb,
    int n,
    const int* __restrict__ esrc, const int* __restrict__ edst,
    const float* __restrict__ evals,
    uint2* __restrict__ slices,        // [nwgA * TILE]
    int* __restrict__ ofs_t,           // [(B+1) * nwgA], transposed [bucket][wg]
    int B, int nwgA, int E)
{
    __shared__ __align__(16) char smem[81920];
    const int tid = threadIdx.x;

    if ((int)blockIdx.x < nwgA) {
        // ------------------- binA: coarse bucket sort -------------------
        int* h   = (int*)smem;
        int* ps  = h + 256;
        int* cur = ps + 256;
        const int wg = blockIdx.x;
        const int e0 = wg * TILE;
        const int e1 = min(e0 + TILE, E);

        h[tid] = 0;
        __syncthreads();
        for (int e = e0 + tid; e < e1; e += 256)
            atomicAdd(&h[edst[e] >> BSHIFT], 1);
        __syncthreads();

        const int v = h[tid];
        ps[tid] = v;
        __syncthreads();
        for (int off = 1; off < 256; off <<= 1) {
            int t = (tid >= off) ? ps[tid - off] : 0;
            __syncthreads();
            if (tid >= off) ps[tid] += t;
            __syncthreads();
        }
        const int excl = ps[tid] - v;
        if (tid < B) {
            cur[tid] = excl;
            ofs_t[(size_t)tid * nwgA + wg] = excl;
        }
        if (tid == 0) ofs_t[(size_t)B * nwgA + wg] = e1 - e0;  // sentinel
        __syncthreads();

        uint2* slice = slices + (size_t)wg * TILE;
        for (int e = e0 + tid; e < e1; e += 256) {
            int d = edst[e];
            int b = d >> BSHIFT;
            int p = atomicAdd(&cur[b], 1);
            uint2 rec;
            rec.x = (unsigned)(d & (BROWS - 1)) | ((unsigned)esrc[e] << BSHIFT);
            rec.y = __float_as_uint(evals[e]);
            slice[p] = rec;
        }
    } else {
        // ------------------- gemm_pack: y = x@W -> bf16 -------------------
        float* sW = (float*)smem;                          // 64 KB
        float (*sA)[128] = (float(*)[128])(smem + 65536);  // 16 KB

        const float4* W4  = (const float4*)W;
        float4*       sW4 = (float4*)sW;
#pragma unroll
        for (int i = 0; i < 16; i++) sW4[tid + 256 * i] = W4[tid + 256 * i];

        const int row0 = (blockIdx.x - nwgA) * 32;
        const float4* A4  = (const float4*)(A + (size_t)row0 * D);
        float4*       sA4 = (float4*)&sA[0][0];
#pragma unroll
        for (int i = 0; i < 4; i++) {
            int idx = tid + 256 * i;
            sA4[idx] = ((size_t)row0 * D + (size_t)idx * 4 < (size_t)n * D)
                           ? A4[idx] : make_float4(0.f, 0.f, 0.f, 0.f);
        }
        __syncthreads();

        const int tx = tid & 31;
        const int ty = tid >> 5;
        const int c0 = tx * 4;

        float acc[4][4] = {};
        for (int k0 = 0; k0 < 128; k0 += 4) {
            float4 a[4];
#pragma unroll
            for (int j = 0; j < 4; j++)
                a[j] = *(const float4*)&sA[ty + 8 * j][k0];
#pragma unroll
            for (int kk = 0; kk < 4; kk++) {
                const float4 w = *(const float4*)&sW[(k0 + kk) * 128 + c0];
                const float ak[4] = { kk == 0 ? a[0].x : kk == 1 ? a[0].y : kk == 2 ? a[0].z : a[0].w,
                                      kk == 0 ? a[1].x : kk == 1 ? a[1].y : kk == 2 ? a[1].z : a[1].w,
                                      kk == 0 ? a[2].x : kk == 1 ? a[2].y : kk == 2 ? a[2].z : a[2].w,
                                      kk == 0 ? a[3].x : kk == 1 ? a[3].y : kk == 2 ? a[3].z : a[3].w };
#pragma unroll
                for (int j = 0; j < 4; j++) {
                    acc[j][0] += ak[j] * w.x;
                    acc[j][1] += ak[j] * w.y;
                    acc[j][2] += ak[j] * w.z;
                    acc[j][3] += ak[j] * w.w;
                }
            }
        }

#pragma unroll
        for (int j = 0; j < 4; j++) {
            const int row = row0 + ty + 8 * j;
            if (row < n) {
                uint2 o;
                o.x = f2bf_rne(acc[j][0]) | (f2bf_rne(acc[j][1]) << 16);
                o.y = f2bf_rne(acc[j][2]) | (f2bf_rne(acc[j][3]) << 16);
                ((uint2*)(yb + (size_t)row * 64))[tx] = o;
            }
        }
    }
}

// ---------------------------------------------------------------------------
// binB: one 1024-thread wg (16 waves) per bucket.
// ---------------------------------------------------------------------------
__global__ __launch_bounds__(1024) void binB_kernel(
    const uint2* __restrict__ slices,
    const int* __restrict__ ofs_t,
    int* __restrict__ rowptr,          // [n], end-form
    ull* __restrict__ csr,             // [E]
    int B, int nwgA, int n)
{
    __shared__ int srow[256];
    __shared__ int erow[256];
    __shared__ int red[256];
    __shared__ int hist[BROWS];
    __shared__ int curs[BROWS];
    __shared__ int ps[BROWS];
    __shared__ int s_bbase;

    const int tid  = threadIdx.x;
    const int b    = blockIdx.x;
    const int w    = tid >> 6;
    const int lane = tid & 63;

    for (int i = tid; i < nwgA; i += 1024) {
        srow[i] = ofs_t[(size_t)b * nwgA + i];
        erow[i] = ofs_t[(size_t)(b + 1) * nwgA + i];
    }
    if (tid < BROWS) hist[tid] = 0;
    __syncthreads();

    if (tid < 256) red[tid] = (tid < nwgA) ? srow[tid] : 0;
    __syncthreads();
    for (int off = 128; off > 0; off >>= 1) {
        if (tid < off) red[tid] += red[tid + off];
        __syncthreads();
    }
    if (tid == 0) s_bbase = red[0];
    __syncthreads();

    // pass 1: in-bucket row histogram
    for (int wg = w; wg < nwgA; wg += 16) {
        const int s = srow[wg];
        const int e = erow[wg];
        const uint2* run = slices + (size_t)wg * TILE;
        for (int i = s + lane; i < e; i += 64)
            atomicAdd(&hist[run[i].x & (BROWS - 1)], 1);
    }
    __syncthreads();

    int v0 = 0;
    if (tid < BROWS) { v0 = hist[tid]; ps[tid] = v0; }
    __syncthreads();
    for (int off = 1; off < BROWS; off <<= 1) {
        int t = 0;
        if (tid < BROWS && tid >= off) t = ps[tid - off];
        __syncthreads();
        if (tid < BROWS) ps[tid] += t;
        __syncthreads();
    }
    if (tid < BROWS) {
        const int excl = s_bbase + ps[tid] - v0;
        curs[tid] = excl;                       // row start
        const int r = (b << BSHIFT) + tid;
        if (r < n) rowptr[r] = excl + v0;       // row end
    }
    __syncthreads();

    // pass 2: scatter into final CSR positions (bucket-private window)
    for (int wg = w; wg < nwgA; wg += 16) {
        const int s = srow[wg];
        const int e = erow[wg];
        const uint2* run = slices + (size_t)wg * TILE;
        for (int i = s + lane; i < e; i += 64) {
            uint2 r = run[i];
            int pos = atomicAdd(&curs[r.x & (BROWS - 1)], 1);
            csr[pos] = ((ull)r.y << 32) | (r.x >> BSHIFT);
        }
    }
}

// ---------------------------------------------------------------------------
// CSR SpMM + fused column stats — round-10: pair-gather.
//
// Round-2 post-mortem: grid 3125 > resident capacity (2048) => 2-round
// dispatch with half-empty tail + doubled stats atomics => regression despite
// higher OccupancyPercent. More blocks is NOT the lever.
//
// Round-10 theory: limiter is per-wave MLP / request-issue rate. Round-0 kept
// only 2KB in flight per wave (8x256B) and spent 2 wave-loads per edge
// (1 broadcast csr + 1 gather). New structure: half-wave q owns row r+q, each
// lane reads uint2 (4 channels); one gather covers TWO edges (512B) and the
// 8-slot unroll keeps 4KB in flight. Validity is UNIFORM per half-wave (no
// divergence machinery; dead slots re-read an L1-hot line with v=0).
// Zero shuffles: half-wave's 32 lanes hold exactly their row's 128 channels.
// Grid back to 1563 (single co-resident round, 400k stats atomics).
// ---------------------------------------------------------------------------
__global__ __launch_bounds__(256) void spmm_stats_kernel(
    const unsigned* __restrict__ yb,
    const int* __restrict__ rowptr,   // end-form
    const ull* __restrict__ csr,
    float* __restrict__ h,
    float* __restrict__ stats,        // [0..127]=sum, [128..255]=sumsq, zeroed
    int n)
{
    __shared__ int   rp[65];
    __shared__ float ssum[128];
    __shared__ float ssq[128];

    const int tid       = threadIdx.x;
    const int blockRow0 = blockIdx.x * 64;
    const int wv        = tid >> 6;
    const int lane      = tid & 63;
    const int half      = lane >> 5;     // which row of the pair
    const int li        = lane & 31;     // owns channels 4*li .. 4*li+3
    const int rbase     = blockRow0 + wv * 16;

    if (tid < 128) { ssum[tid] = 0.f; ssq[tid] = 0.f; }
    if (tid < 65) {
        int idx = blockRow0 + tid - 1;          // row whose END we need
        rp[tid] = (idx < 0) ? 0 : rowptr[min(idx, n - 1)];
    }
    __syncthreads();

    float s0 = 0.f, s1 = 0.f, s2 = 0.f, s3 = 0.f;
    float q0 = 0.f, q1 = 0.f, q2 = 0.f, q3 = 0.f;

    if (rbase < n) {
        for (int pr = 0; pr < 16; pr += 2) {
            const int  rA    = rbase + pr + half;     // this half's row
            const bool rowOK = rA < n;
            const int  s_    = rowOK ? rp[rA - blockRow0]     : 0;
            const int  e_    = rowOK ? rp[rA - blockRow0 + 1] : 0;
            const int  nA    = e_ - s_;
            // trip count: max of the two halves' row lengths
            const int  nMax  = max(nA, __shfl_xor(nA, 32));

            float a0 = 0.f, a1 = 0.f, a2 = 0.f, a3 = 0.f;
            for (int i = 0; i < nMax; i += 8) {
                ull cd[8];
#pragma unroll
                for (int j = 0; j < 8; j++) {
                    int idx = s_ + i + j;
                    int ce  = (idx < e_) ? idx : (nA ? e_ - 1 : 0);
                    cd[j] = csr[ce];
                }
                uint2 u[8];
                float v[8];
#pragma unroll
                for (int j = 0; j < 8; j++) {
                    u[j] = *(const uint2*)(yb + (size_t)(unsigned)cd[j] * 64 + 2 * li);
                    v[j] = (s_ + i + j < e_)
                               ? __uint_as_float((unsigned)(cd[j] >> 32))
                               : 0.f;
                }
#pragma unroll
                for (int j = 0; j < 8; j++) {
                    a0 += v[j] * bf_lo(u[j].x);
                    a1 += v[j] * bf_hi(u[j].x);
                    a2 += v[j] * bf_lo(u[j].y);
                    a3 += v[j] * bf_hi(u[j].y);
                }
            }

            if (rowOK) {
                *(float4*)&h[(size_t)rA * D + 4 * li] = make_float4(a0, a1, a2, a3);
                s0 += a0; s1 += a1; s2 += a2; s3 += a3;
                q0 += a0 * a0; q1 += a1 * a1; q2 += a2 * a2; q3 += a3 * a3;
            }
        }

        atomicAdd(&ssum[4 * li + 0], s0); atomicAdd(&ssum[4 * li + 1], s1);
        atomicAdd(&ssum[4 * li + 2], s2); atomicAdd(&ssum[4 * li + 3], s3);
        atomicAdd(&ssq [4 * li + 0], q0); atomicAdd(&ssq [4 * li + 1], q1);
        atomicAdd(&ssq [4 * li + 2], q2); atomicAdd(&ssq [4 * li + 3], q3);
    }
    __syncthreads();
    if (tid < 128) {
        atomicAdd(&stats[tid],       ssum[tid]);
        atomicAdd(&stats[128 + tid], ssq[tid]);
    }
}

// ---------------------------------------------------------------------------
// In-place BatchNorm apply. Linear bias cancels under BN -> omitted.
// ---------------------------------------------------------------------------
__global__ __launch_bounds__(256) void bn_apply_kernel(
    float* __restrict__ h,
    const float* __restrict__ stats,
    const float* __restrict__ gamma,
    const float* __restrict__ beta,
    int n)
{
    __shared__ float s_scale[128];
    __shared__ float s_shift[128];
    const int tid = threadIdx.x;
    if (tid < 128) {
        const float invn = 1.0f / (float)n;
        const float mean = stats[tid] * invn;
        const float var  = stats[128 + tid] * invn - mean * mean;
        const float inv  = rsqrtf(var + BN_EPS);
        const float g    = gamma[tid] * inv;
        s_scale[tid] = g;
        s_shift[tid] = beta[tid] - mean * g;
    }
    __syncthreads();

    float4* h4 = (float4*)h;
    const size_t total = (size_t)n * D / 4;
    const size_t stride = (size_t)gridDim.x * blockDim.x;
    for (size_t i = (size_t)blockIdx.x * blockDim.x + tid; i < total; i += stride) {
        float4 v = h4[i];
        const int c = (int)((i * 4) & (D - 1));
        v.x = v.x * s_scale[c]     + s_shift[c];
        v.y = v.y * s_scale[c + 1] + s_shift[c + 1];
        v.z = v.z * s_scale[c + 2] + s_shift[c + 2];
        v.w = v.w * s_scale[c + 3] + s_shift[c + 3];
        h4[i] = v;
    }
}

// ---------------------------------------------------------------------------
// Fallback (ws too small / shape mismatch): atomic SpMM + GEMM w/ stats.
// ---------------------------------------------------------------------------
__global__ __launch_bounds__(256) void spmm_atomic_kernel(
    const float* __restrict__ x,
    const int* __restrict__ esrc, const int* __restrict__ edst,
    const float* __restrict__ eval, float* __restrict__ agg, int E)
{
    int wave  = (blockIdx.x * blockDim.x + threadIdx.x) >> 6;
    int lane  = threadIdx.x & 63;
    int nwave = (gridDim.x * blockDim.x) >> 6;
    for (int e = wave; e < E; e += nwave) {
        int   s = esrc[e];
        int   d = edst[e];
        float v = eval[e];
        const float2 xv = ((const float2*)(x + (size_t)s * D))[lane];
        float* ar = agg + (size_t)d * D + lane * 2;
        atomicAdd(ar,     xv.x * v);
        atomicAdd(ar + 1, xv.y * v);
    }
}

__global__ __launch_bounds__(256) void gemm_stats_kernel(
    const float* __restrict__ A,
    const float* __restrict__ W,
    float* __restrict__ h,
    float* __restrict__ stats,
    int n)
{
    __shared__ float sW[128 * 128];
    __shared__ float sA[32][128];
    const int tid = threadIdx.x;
    const float4* W4  = (const float4*)W;
    float4*       sW4 = (float4*)sW;
#pragma unroll
    for (int i = 0; i < 16; i++) sW4[tid + 256 * i] = W4[tid + 256 * i];
    const int row0 = blockIdx.x * 32;
    const float4* A4  = (const float4*)(A + (size_t)row0 * D);
    float4*       sA4 = (float4*)&sA[0][0];
#pragma unroll
    for (int i = 0; i < 4; i++) {
        int idx = tid + 256 * i;
        sA4[idx] = ((size_t)row0 * D + (size_t)idx * 4 < (size_t)n * D)
                       ? A4[idx] : make_float4(0.f, 0.f, 0.f, 0.f);
    }
    __syncthreads();
    const int tx = tid & 31, ty = tid >> 5, c0 = tx * 4;
    float acc[4][4] = {};
    for (int k = 0; k < 128; k++) {
        const float4 w = *(const float4*)&sW[k * 128 + c0];
#pragma unroll
        for (int j = 0; j < 4; j++) {
            const float a = sA[ty + 8 * j][k];
            acc[j][0] += a * w.x; acc[j][1] += a * w.y;
            acc[j][2] += a * w.z; acc[j][3] += a * w.w;
        }
    }
#pragma unroll
    for (int j = 0; j < 4; j++) {
        const int row = row0 + ty + 8 * j;
        if (row < n)
            *(float4*)&h[(size_t)row * D + c0] =
                make_float4(acc[j][0], acc[j][1], acc[j][2], acc[j][3]);
    }
    __syncthreads();
    float* csum = &sA[0][0];
    float* csq  = csum + 128;
    if (tid < 128) { csum[tid] = 0.f; csq[tid] = 0.f; }
    __syncthreads();
#pragma unroll
    for (int c = 0; c < 4; c++) {
        float s = 0.f, q = 0.f;
#pragma unroll
        for (int j = 0; j < 4; j++) { s += acc[j][c]; q += acc[j][c] * acc[j][c]; }
        atomicAdd(&csum[c0 + c], s);
        atomicAdd(&csq[c0 + c], q);
    }
    __syncthreads();
    if (tid < 128) {
        atomicAdd(&stats[tid],       csum[tid]);
        atomicAdd(&stats[128 + tid], csq[tid]);
    }
}

// ---------------------------------------------------------------------------
extern "C" void kernel_launch(void* const* d_in, const int* in_sizes, int n_in,
                              void* d_out, int out_size, void* d_ws, size_t ws_size,
                              hipStream_t stream)
{
    const float* x     = (const float*)d_in[0];
    const int*   esrc  = (const int*)d_in[1];
    const int*   edst  = (const int*)d_in[2];
    const float* evals = (const float*)d_in[3];
    const float* W     = (const float*)d_in[4];
    // d_in[5] = bias: unused — cancels exactly under BatchNorm.
    const float* gamma = (const float*)d_in[6];
    const float* beta  = (const float*)d_in[7];
    float* out = (float*)d_out;

    const int n = in_sizes[0] / D;   // 100000
    const int E = in_sizes[1];       // 1600000

    const int B     = (n + BROWS - 1) >> BSHIFT;   // 196 buckets
    const int nwgA  = (E + TILE - 1) / TILE;       // 196 tiles
    const int ngemm = (n + 31) / 32;               // 3125 gemm blocks

    // Workspace (word-indexed):
    //   yb      [n*64]            25.6 MB (packed bf16 y = x@W)
    //   stats   [256]             zeroed (1KB memset)
    //   ofs_t   [(B+1)*nwgA]      ~155 KB (transposed: [bucket][wg])
    //   rowptr  [n]
    //   (pad to even word)
    //   slices  uint2[nwgA*TILE]  12.85 MB
    //   csr     ull  [E]          12.8 MB
    unsigned* yb     = (unsigned*)d_ws;
    float*    stats  = (float*)(yb + (size_t)n * 64);
    int*      ofs_t  = (int*)(stats + 256);
    int*      rowptr = ofs_t + (size_t)(B + 1) * nwgA;
    size_t    w_off  = (size_t)n * 64 + 256 + (size_t)(B + 1) * nwgA + n;
    w_off += (w_off & 1);                          // 8B alignment
    uint2*    slices = (uint2*)((unsigned*)d_ws + w_off);
    ull*      csr    = (ull*)(slices + (size_t)nwgA * TILE);
    const size_t need = (w_off + (size_t)nwgA * TILE * 2 + (size_t)E * 2) * 4;

    if (ws_size >= need && B <= 256 && nwgA <= 256) {
        hipMemsetAsync(stats, 0, 256 * 4, stream);
        phase1_kernel<<<nwgA + ngemm, 256, 0, stream>>>(
            x, W, yb, n, esrc, edst, evals, slices, ofs_t, B, nwgA, E);
        binB_kernel<<<B, 1024, 0, stream>>>(
            slices, ofs_t, rowptr, csr, B, nwgA, n);
        spmm_stats_kernel<<<(n + 63) / 64, 256, 0, stream>>>(
            yb, rowptr, csr, out, stats, n);
        bn_apply_kernel<<<2048, 256, 0, stream>>>(out, stats, gamma, beta, n);
    } else {
        // fallback: fp32 atomic-scatter path
        float* agg = (float*)d_ws;
        float* st  = agg + (size_t)n * D;
        hipMemsetAsync(d_ws, 0, ((size_t)n * D + 256) * 4, stream);
        spmm_atomic_kernel<<<4096, 256, 0, stream>>>(x, esrc, edst, evals, agg, E);
        gemm_stats_kernel<<<(n + 31) / 32, 256, 0, stream>>>(agg, W, out, st, n);
        bn_apply_kernel<<<2048, 256, 0, stream>>>(out, st, gamma, beta, n);
    }
}